// Round 2
// baseline (232.016 us; speedup 1.0000x reference)
//
#include <hip/hip_runtime.h>
#include <hip/hip_bf16.h>

// out[r][c] = x[r][c] * clamp(w[c], 0, 1)
// ROWS=8192, IN_FEATURES=4096, fp32 in/out. Pure memory-bound elementwise scale.
//
// Vectorized float4 path: 8192*4096/4 = 8,388,608 float4 elements.
// IN_FEATURES/4 = 1024 (power of 2) -> weight float4 index = i & 1023.
// Grid-stride loop, 2048 blocks x 256 threads (G11 guideline).

#define IN_FEATURES 4096
#define ROWS 8192
#define NVEC (ROWS * IN_FEATURES / 4)   // float4 count
#define WVEC (IN_FEATURES / 4)          // 1024, power of two

__global__ __launch_bounds__(256) void scale_cols_kernel(
    const float4* __restrict__ x,
    const float4* __restrict__ w,
    float4* __restrict__ out)
{
    int64_t stride = (int64_t)gridDim.x * blockDim.x;
    for (int64_t i = (int64_t)blockIdx.x * blockDim.x + threadIdx.x;
         i < (int64_t)NVEC; i += stride) {
        float4 xv = x[i];
        float4 wv = w[i & (WVEC - 1)];   // weights tiny -> L1/L2 resident
        float4 o;
        o.x = xv.x * fminf(fmaxf(wv.x, 0.0f), 1.0f);
        o.y = xv.y * fminf(fmaxf(wv.y, 0.0f), 1.0f);
        o.z = xv.z * fminf(fmaxf(wv.z, 0.0f), 1.0f);
        o.w = xv.w * fminf(fmaxf(wv.w, 0.0f), 1.0f);
        out[i] = o;
    }
}

extern "C" void kernel_launch(void* const* d_in, const int* in_sizes, int n_in,
                              void* d_out, int out_size, void* d_ws, size_t ws_size,
                              hipStream_t stream) {
    const float4* x = (const float4*)d_in[0];   // [ROWS, IN_FEATURES] fp32
    const float4* w = (const float4*)d_in[1];   // [IN_FEATURES] fp32
    float4* out = (float4*)d_out;               // [ROWS, IN_FEATURES] fp32

    const int block = 256;
    const int grid = 2048;   // 256 CUs * 8 blocks/CU; grid-stride covers the rest
    scale_cols_kernel<<<grid, block, 0, stream>>>(x, w, out);
}

// Round 6
// 230.217 us; speedup vs baseline: 1.0078x; 1.0078x over previous
//
#include <hip/hip_runtime.h>
#include <hip/hip_bf16.h>

// out[r][c] = x[r][c] * clamp(w[c], 0, 1)
// ROWS=8192, IN_FEATURES=4096, fp32 in/out. Memory-bound elementwise scale.
//
// R2 theory (vs R1's 80us @ ~3.3 TB/s effective): grid-stride loop had ~1
// load in flight per thread (latency-bound, not BW-bound). Fix: exact
// tiling, 8 INDEPENDENT 16B loads per thread issued back-to-back, weights
// hoisted to 4 registers (col = t + 256*(k&3), loop-invariant), nontemporal
// stores for out (bypass L3 write-alloc so L3 keeps serving x reads).
//
// R5 fix: __builtin_nontemporal_store rejects HIP_vector_type<float,4>* —
// use native ext_vector_type(4) float instead (same dwordx4 codegen).

#define IN_FEATURES 4096
#define ROWS 8192
#define NVEC (ROWS * IN_FEATURES / 4)   // 8,388,608 vec4
#define WVEC (IN_FEATURES / 4)          // 1024 vec4 (power of two)
#define PER_THREAD 8
#define BLOCK 256
// block tile = 256*8 = 2048 vec4; grid = 8388608/2048 = 4096 blocks exactly

typedef float vfloat4 __attribute__((ext_vector_type(4)));

__global__ __launch_bounds__(BLOCK) void scale_cols_kernel(
    const vfloat4* __restrict__ x,
    const vfloat4* __restrict__ w,
    vfloat4* __restrict__ out)
{
    const int t = threadIdx.x;
    const int64_t base = (int64_t)blockIdx.x * (BLOCK * PER_THREAD) + t;

    // Weight vec4 column for element k is (t + 256*k) & 1023 = t + 256*(k&3).
    // Load + clamp the 4 distinct weight vectors once.
    vfloat4 wv[4];
#pragma unroll
    for (int j = 0; j < 4; ++j) {
        vfloat4 v = w[(t + BLOCK * j) & (WVEC - 1)];
#pragma unroll
        for (int e = 0; e < 4; ++e)
            v[e] = fminf(fmaxf(v[e], 0.0f), 1.0f);
        wv[j] = v;
    }

    // 8 independent loads in flight (8 KiB/wave outstanding).
    vfloat4 xv[PER_THREAD];
#pragma unroll
    for (int k = 0; k < PER_THREAD; ++k)
        xv[k] = x[base + (int64_t)BLOCK * k];

#pragma unroll
    for (int k = 0; k < PER_THREAD; ++k) {
        vfloat4 o = xv[k] * wv[k & 3];
        __builtin_nontemporal_store(o, &out[base + (int64_t)BLOCK * k]);
    }
}

extern "C" void kernel_launch(void* const* d_in, const int* in_sizes, int n_in,
                              void* d_out, int out_size, void* d_ws, size_t ws_size,
                              hipStream_t stream) {
    const vfloat4* x = (const vfloat4*)d_in[0];   // [ROWS, IN_FEATURES] fp32
    const vfloat4* w = (const vfloat4*)d_in[1];   // [IN_FEATURES] fp32
    vfloat4* out = (vfloat4*)d_out;               // [ROWS, IN_FEATURES] fp32

    const int grid = NVEC / (BLOCK * PER_THREAD);  // 4096
    scale_cols_kernel<<<grid, BLOCK, 0, stream>>>(x, w, out);
}

// Round 8
// 222.610 us; speedup vs baseline: 1.0423x; 1.0342x over previous
//
#include <hip/hip_runtime.h>
#include <hip/hip_bf16.h>

// out[r][c] = x[r][c] * clamp(w[c], 0, 1)
// ROWS=8192, IN_FEATURES=4096, fp32 in/out. Memory-bound elementwise scale.
//
// History: R1 grid-stride = 79.6us; R6 8-deep-ILP = 79.2us (identical!) at
// 2.5 TB/s HBM while fill hits 6.7 and m13 copy hits 6.3. ILP is not the
// lever. R7 tests: (a) persistent blocks (2048 = 8/CU), software-pipelined
// load-B-before-store-A so the read stream never idles during store drain;
// (b) nontemporal LOADS on x (stop L3 read-alloc churn against the write
// stream; hits still hit); normal stores (nt-store was null R1 vs R6).

#define IN_FEATURES 4096
#define ROWS 8192
#define NVEC (ROWS * IN_FEATURES / 4)   // 8,388,608 vec4
#define WVEC (IN_FEATURES / 4)          // 1024 vec4 (power of two)
#define BLOCK 256
#define GRID 2048                        // 8 blocks/CU -> 32 waves/CU resident
#define BATCH 8
// per-thread total = NVEC/(GRID*BLOCK) = 16 vec4 = 2 batches of 8

typedef float vfloat4 __attribute__((ext_vector_type(4)));

__global__ __launch_bounds__(BLOCK) void scale_cols_kernel(
    const vfloat4* __restrict__ x,
    const vfloat4* __restrict__ w,
    vfloat4* __restrict__ out)
{
    const int t = threadIdx.x;
    // block tile = BLOCK*BATCH*2 = 4096 vec4 = 64 KB contiguous
    const int64_t base = (int64_t)blockIdx.x * (BLOCK * BATCH * 2) + t;

    // Weight vec4 col for elem k of either batch: (t + 256*k) & 1023
    // (batch/block offsets are multiples of 1024). 4 distinct vectors.
    vfloat4 wv[4];
#pragma unroll
    for (int j = 0; j < 4; ++j) {
        vfloat4 v = w[(t + BLOCK * j) & (WVEC - 1)];
#pragma unroll
        for (int e = 0; e < 4; ++e)
            v[e] = fminf(fmaxf(v[e], 0.0f), 1.0f);
        wv[j] = v;
    }

    // Batch A loads (nontemporal: streaming, no L3 alloc churn)
    vfloat4 a[BATCH], b[BATCH];
#pragma unroll
    for (int k = 0; k < BATCH; ++k)
        a[k] = __builtin_nontemporal_load(&x[base + (int64_t)BLOCK * k]);

    // Issue batch B loads BEFORE storing batch A: reads stay outstanding
    // while A's stores drain.
#pragma unroll
    for (int k = 0; k < BATCH; ++k)
        b[k] = __builtin_nontemporal_load(&x[base + BLOCK * BATCH + (int64_t)BLOCK * k]);

#pragma unroll
    for (int k = 0; k < BATCH; ++k)
        out[base + (int64_t)BLOCK * k] = a[k] * wv[k & 3];

#pragma unroll
    for (int k = 0; k < BATCH; ++k)
        out[base + BLOCK * BATCH + (int64_t)BLOCK * k] = b[k] * wv[k & 3];
}

extern "C" void kernel_launch(void* const* d_in, const int* in_sizes, int n_in,
                              void* d_out, int out_size, void* d_ws, size_t ws_size,
                              hipStream_t stream) {
    const vfloat4* x = (const vfloat4*)d_in[0];   // [ROWS, IN_FEATURES] fp32
    const vfloat4* w = (const vfloat4*)d_in[1];   // [IN_FEATURES] fp32
    vfloat4* out = (vfloat4*)d_out;               // [ROWS, IN_FEATURES] fp32

    scale_cols_kernel<<<GRID, BLOCK, 0, stream>>>(x, w, out);
}

// Round 10
// 222.367 us; speedup vs baseline: 1.0434x; 1.0011x over previous
//
#include <hip/hip_runtime.h>
#include <hip/hip_bf16.h>

// out[r][c] = x[r][c] * clamp(w[c], 0, 1)
// ROWS=8192, IN_FEATURES=4096, fp32 in/out. Memory-bound elementwise scale.
//
// History: R1 grid-stride = 79.6us; R6 8-deep-ILP = 79.2us; R7 persistent
// grid + load-B-before-store-A pipeline + nt LOADS => kernel dropped below
// the 79us fills (dur_us 230->222). Theory: the harness's ~536MB poison
// fill drains from L3 to HBM concurrently with our kernel, sharing the bus.
// R9: also bypass L3 on the STORE side (__builtin_nontemporal_store) so our
// 134MB of writes don't churn L3 against the drain. Full streaming kernel.

#define IN_FEATURES 4096
#define ROWS 8192
#define NVEC (ROWS * IN_FEATURES / 4)   // 8,388,608 vec4
#define WVEC (IN_FEATURES / 4)          // 1024 vec4 (power of two)
#define BLOCK 256
#define GRID 2048                        // 8 blocks/CU, persistent-ish
#define BATCH 8
// per-thread total = NVEC/(GRID*BLOCK) = 16 vec4 = 2 batches of 8

typedef float vfloat4 __attribute__((ext_vector_type(4)));

__global__ __launch_bounds__(BLOCK) void scale_cols_kernel(
    const vfloat4* __restrict__ x,
    const vfloat4* __restrict__ w,
    vfloat4* __restrict__ out)
{
    const int t = threadIdx.x;
    // block tile = BLOCK*BATCH*2 = 4096 vec4 = 64 KB contiguous
    const int64_t base = (int64_t)blockIdx.x * (BLOCK * BATCH * 2) + t;

    // Weight vec4 col for elem k of either batch: (t + 256*k) & 1023
    // (batch/block offsets are multiples of 1024). 4 distinct vectors.
    vfloat4 wv[4];
#pragma unroll
    for (int j = 0; j < 4; ++j) {
        vfloat4 v = w[(t + BLOCK * j) & (WVEC - 1)];
#pragma unroll
        for (int e = 0; e < 4; ++e)
            v[e] = fminf(fmaxf(v[e], 0.0f), 1.0f);
        wv[j] = v;
    }

    // 16 independent nt loads in flight before any store (16 KiB/wave).
    vfloat4 a[BATCH], b[BATCH];
#pragma unroll
    for (int k = 0; k < BATCH; ++k)
        a[k] = __builtin_nontemporal_load(&x[base + (int64_t)BLOCK * k]);
#pragma unroll
    for (int k = 0; k < BATCH; ++k)
        b[k] = __builtin_nontemporal_load(&x[base + BLOCK * BATCH + (int64_t)BLOCK * k]);

    // Nontemporal stores: no L3 write-allocate, no churn against the
    // harness poison-fill drain.
#pragma unroll
    for (int k = 0; k < BATCH; ++k) {
        vfloat4 o = a[k] * wv[k & 3];
        __builtin_nontemporal_store(o, &out[base + (int64_t)BLOCK * k]);
    }
#pragma unroll
    for (int k = 0; k < BATCH; ++k) {
        vfloat4 o = b[k] * wv[k & 3];
        __builtin_nontemporal_store(o, &out[base + BLOCK * BATCH + (int64_t)BLOCK * k]);
    }
}

extern "C" void kernel_launch(void* const* d_in, const int* in_sizes, int n_in,
                              void* d_out, int out_size, void* d_ws, size_t ws_size,
                              hipStream_t stream) {
    const vfloat4* x = (const vfloat4*)d_in[0];   // [ROWS, IN_FEATURES] fp32
    const vfloat4* w = (const vfloat4*)d_in[1];   // [IN_FEATURES] fp32
    vfloat4* out = (vfloat4*)d_out;               // [ROWS, IN_FEATURES] fp32

    scale_cols_kernel<<<GRID, BLOCK, 0, stream>>>(x, w, out);
}